// Round 11
// baseline (348.999 us; speedup 1.0000x reference)
//
#include <hip/hip_runtime.h>
#include <cstdint>
#include <cstddef>

// ---------------------------------------------------------------------------
// RestrictedTransformerEncoderLayer on MI355X (gfx950)  — ROUND 11
// B=2, L=2048, E=1024, H=16, D=64, FF=4096, WIN=128.
// External I/O f32; intermediates bf16; output f32.
// R11: FF2 split-K=2 (gridDim.z=2, 1024 blocks = 4 blocks/CU) with f32
// atomicAdd into pre-zeroed d_out. R10 showed FF2 grid-capped at 2 blocks/CU
// (Occ 19.6%), latency-bound at every barrier drain.
// Workspace (peak 50.33 MB):
//   srcb/x1b bf16 [0,        8388608)   (LN1 in-place over srcb)
//   qkv  bf16     [8388608,  33554432)  dead after attn
//   ctx  bf16     [33554432, 41943040)  dead after out-proj
//   attnb bf16    [8388608,  16777216)  (reuse qkv)  dead after LN1
//   ff1  bf16     [8388608,  41943040)
//   wslot bf16    [41943040, 50331648)  converted weight (serial reuse)
// ---------------------------------------------------------------------------

typedef __attribute__((ext_vector_type(8))) short short8;   // 8 x bf16 MFMA frag
typedef __attribute__((ext_vector_type(4))) float f32x4;    // MFMA accumulator

__device__ __forceinline__ float b2f(unsigned short u) {
  union { unsigned int i; float f; } x; x.i = ((unsigned int)u) << 16; return x.f;
}
__device__ __forceinline__ unsigned short f2b(float f) {
  union { float f; unsigned int i; } x; x.f = f;
  unsigned int i = x.i;
  unsigned int r = (i + 0x7FFFu + ((i >> 16) & 1u)) >> 16;  // RNE
  return (unsigned short)r;
}
__device__ __forceinline__ uint4 pack8(float4 f0, float4 f1) {
  uint4 r;
  r.x = (unsigned)f2b(f0.x) | ((unsigned)f2b(f0.y) << 16);
  r.y = (unsigned)f2b(f0.z) | ((unsigned)f2b(f0.w) << 16);
  r.z = (unsigned)f2b(f1.x) | ((unsigned)f2b(f1.y) << 16);
  r.w = (unsigned)f2b(f1.z) | ((unsigned)f2b(f1.w) << 16);
  return r;
}

// async global->LDS, 16B/lane; LDS base wave-uniform, lanes write base+lane*16
__device__ __forceinline__ void gl_lds16(const unsigned short* g, unsigned short* l) {
  __builtin_amdgcn_global_load_lds(
      (const __attribute__((address_space(1))) unsigned int*)g,
      (__attribute__((address_space(3))) unsigned int*)l, 16, 0, 0);
}

// ---------------------------------------------------------------------------
// f32 -> bf16 convert
// ---------------------------------------------------------------------------
__global__ __launch_bounds__(256) void conv_k(
    const float* __restrict__ in, unsigned short* __restrict__ out, int n)
{
  const int i = (blockIdx.x * 256 + threadIdx.x) * 8;
  if (i < n) {
    const float4 f0 = *(const float4*)(in + i);
    const float4 f1 = *(const float4*)(in + i + 4);
    *(uint4*)(out + i) = pack8(f0, f1);
  }
}

// ---------------------------------------------------------------------------
// GEMM 128x128 tile, BK=64 (unchanged from passing r10).
// Swizzle: slot s of row r holds chunk (s+r)&7; reader (c-r)&7. Conflict-free.
// ---------------------------------------------------------------------------
template<int RELU, int OUT32>
__global__ __launch_bounds__(256) void gemm128(
    const unsigned short* __restrict__ A, const unsigned short* __restrict__ Wb,
    const float* __restrict__ bias, void* __restrict__ out,
    int M, int N, int K)
{
  __shared__ unsigned short As[128 * 64];   // 16 KB
  __shared__ unsigned short Bs[128 * 64];   // 16 KB

  const int tid = threadIdx.x;
  const int lane = tid & 63, wid = tid >> 6;
  const int m0 = blockIdx.y * 128, n0 = blockIdx.x * 128;

  const unsigned short* gA[4];
  const unsigned short* gW[4];
  int ldsO[4];
#pragma unroll
  for (int i = 0; i < 4; ++i) {
    const int sl = wid * 256 + i * 64 + lane;
    const int r = sl >> 3, s = sl & 7, c = (s + r) & 7;
    gA[i] = A + (size_t)(m0 + r) * K + c * 8;
    gW[i] = Wb + (size_t)(n0 + r) * K + c * 8;
    ldsO[i] = (wid * 256 + i * 64) * 8;
  }

  const int cl = lane & 15;
  const int kg = lane >> 4;
  const int msub = (wid >> 1) * 64, nsub = (wid & 1) * 64;
  int aoff[4][2], boff[4][2];
#pragma unroll
  for (int t = 0; t < 4; ++t) {
    const int ar = msub + t * 16 + cl;
    const int br = nsub + t * 16 + cl;
#pragma unroll
    for (int ks = 0; ks < 2; ++ks) {
      aoff[t][ks] = ar * 64 + ((ks * 4 + kg - ar) & 7) * 8;
      boff[t][ks] = br * 64 + ((ks * 4 + kg - br) & 7) * 8;
    }
  }

  f32x4 acc[4][4];
#pragma unroll
  for (int i = 0; i < 4; ++i)
#pragma unroll
    for (int j = 0; j < 4; ++j) acc[i][j] = (f32x4){0.f, 0.f, 0.f, 0.f};

  const int steps = K >> 6;
  for (int s = 0; s < steps; ++s) {
#pragma unroll
    for (int i = 0; i < 4; ++i) { gl_lds16(gA[i], &As[ldsO[i]]); gA[i] += 64; }
#pragma unroll
    for (int i = 0; i < 4; ++i) { gl_lds16(gW[i], &Bs[ldsO[i]]); gW[i] += 64; }
    __syncthreads();

    short8 af[4][2], bf[4][2];
#pragma unroll
    for (int t = 0; t < 4; ++t)
#pragma unroll
      for (int ks = 0; ks < 2; ++ks) {
        af[t][ks] = *(const short8*)&As[aoff[t][ks]];
        bf[t][ks] = *(const short8*)&Bs[boff[t][ks]];
      }
#pragma unroll
    for (int mt = 0; mt < 4; ++mt)
#pragma unroll
      for (int nt = 0; nt < 4; ++nt)
#pragma unroll
        for (int ks = 0; ks < 2; ++ks)
          acc[mt][nt] = __builtin_amdgcn_mfma_f32_16x16x32_bf16(af[mt][ks], bf[nt][ks], acc[mt][nt], 0, 0, 0);
    __syncthreads();
  }

#pragma unroll
  for (int nt = 0; nt < 4; ++nt) {
    const int col = n0 + nsub + nt * 16 + cl;
    const float bvs = bias[col];
#pragma unroll
    for (int mt = 0; mt < 4; ++mt) {
#pragma unroll
      for (int r = 0; r < 4; ++r) {
        const int grow = m0 + msub + mt * 16 + kg * 4 + r;
        float v = acc[mt][nt][r] + bvs;
        if (RELU) v = fmaxf(v, 0.f);
        if (OUT32) ((float*)out)[(size_t)grow * N + col] = v;
        else       ((unsigned short*)out)[(size_t)grow * N + col] = f2b(v);
      }
    }
  }
}

// ---------------------------------------------------------------------------
// GEMM 64x128 tile, BK=64, optional split-K via gridDim.z.
// ATOMIC: each z-slice covers K/gridDim.z; results combined by f32 atomicAdd
// into pre-zeroed out (bias added by z==0 slice only).
// ---------------------------------------------------------------------------
template<int OUT32, int ATOMIC>
__global__ __launch_bounds__(256) void gemm64(
    const unsigned short* __restrict__ A, const unsigned short* __restrict__ Wb,
    const float* __restrict__ bias, void* __restrict__ out,
    int M, int N, int K)
{
  __shared__ unsigned short As[64 * 64];    // 8 KB
  __shared__ unsigned short Bs[128 * 64];   // 16 KB

  const int tid = threadIdx.x;
  const int lane = tid & 63, wid = tid >> 6;
  const int m0 = blockIdx.y * 64, n0 = blockIdx.x * 128;
  const int kz = blockIdx.z;
  const int Klen = K / gridDim.z;
  const int kbase = kz * Klen;

  const unsigned short* gA[2];
  const unsigned short* gW[4];
  int ldsA[2], ldsB[4];
#pragma unroll
  for (int i = 0; i < 2; ++i) {
    const int sl = wid * 128 + i * 64 + lane;
    const int r = sl >> 3, s = sl & 7, c = (s + r) & 7;
    gA[i] = A + (size_t)(m0 + r) * K + kbase + c * 8;
    ldsA[i] = (wid * 128 + i * 64) * 8;
  }
#pragma unroll
  for (int i = 0; i < 4; ++i) {
    const int sl = wid * 256 + i * 64 + lane;
    const int r = sl >> 3, s = sl & 7, c = (s + r) & 7;
    gW[i] = Wb + (size_t)(n0 + r) * K + kbase + c * 8;
    ldsB[i] = (wid * 256 + i * 64) * 8;
  }

  const int cl = lane & 15;
  const int kg = lane >> 4;
  int aoff[4][2], boff[2][2];
#pragma unroll
  for (int t = 0; t < 4; ++t) {
    const int ar = t * 16 + cl;
#pragma unroll
    for (int ks = 0; ks < 2; ++ks)
      aoff[t][ks] = ar * 64 + ((ks * 4 + kg - ar) & 7) * 8;
  }
#pragma unroll
  for (int t = 0; t < 2; ++t) {
    const int br = wid * 32 + t * 16 + cl;
#pragma unroll
    for (int ks = 0; ks < 2; ++ks)
      boff[t][ks] = br * 64 + ((ks * 4 + kg - br) & 7) * 8;
  }

  f32x4 acc[4][2];
#pragma unroll
  for (int i = 0; i < 4; ++i)
#pragma unroll
    for (int j = 0; j < 2; ++j) acc[i][j] = (f32x4){0.f, 0.f, 0.f, 0.f};

  const int steps = Klen >> 6;
  for (int s = 0; s < steps; ++s) {
#pragma unroll
    for (int i = 0; i < 2; ++i) { gl_lds16(gA[i], &As[ldsA[i]]); gA[i] += 64; }
#pragma unroll
    for (int i = 0; i < 4; ++i) { gl_lds16(gW[i], &Bs[ldsB[i]]); gW[i] += 64; }
    __syncthreads();

    short8 af[4][2], bf[2][2];
#pragma unroll
    for (int t = 0; t < 4; ++t)
#pragma unroll
      for (int ks = 0; ks < 2; ++ks) af[t][ks] = *(const short8*)&As[aoff[t][ks]];
#pragma unroll
    for (int t = 0; t < 2; ++t)
#pragma unroll
      for (int ks = 0; ks < 2; ++ks) bf[t][ks] = *(const short8*)&Bs[boff[t][ks]];
#pragma unroll
    for (int mt = 0; mt < 4; ++mt)
#pragma unroll
      for (int nt = 0; nt < 2; ++nt)
#pragma unroll
        for (int ks = 0; ks < 2; ++ks)
          acc[mt][nt] = __builtin_amdgcn_mfma_f32_16x16x32_bf16(af[mt][ks], bf[nt][ks], acc[mt][nt], 0, 0, 0);
    __syncthreads();
  }

#pragma unroll
  for (int nt = 0; nt < 2; ++nt) {
    const int col = n0 + wid * 32 + nt * 16 + cl;
    const float bvs = (!ATOMIC || kz == 0) ? bias[col] : 0.f;
#pragma unroll
    for (int mt = 0; mt < 4; ++mt) {
#pragma unroll
      for (int r = 0; r < 4; ++r) {
        const int grow = m0 + mt * 16 + kg * 4 + r;
        const float v = acc[mt][nt][r] + bvs;
        if (ATOMIC)      atomicAdd(&((float*)out)[(size_t)grow * N + col], v);
        else if (OUT32)  ((float*)out)[(size_t)grow * N + col] = v;
        else             ((unsigned short*)out)[(size_t)grow * N + col] = f2b(v);
      }
    }
  }
}

// ---------------------------------------------------------------------------
// MFMA flash attention (unchanged from passing r6-r10).
// ---------------------------------------------------------------------------
__global__ __launch_bounds__(256) void attn_mfma(
    const unsigned short* __restrict__ qkv, unsigned short* __restrict__ ctx)
{
  __shared__ unsigned short Ks[64 * 72];
  __shared__ unsigned short Vt[64 * 72];
  __shared__ unsigned short Ps[64 * 72];

  const int tid = threadIdx.x;
  const int bid = blockIdx.x;
  const int qt = bid & 31, h = (bid >> 5) & 15, b = bid >> 9;
  const int q0 = qt * 64;
  const int wstart = max(0, q0 - 128);
  const int wend = min(2048, q0 + 64 + 128);
  const int ntile = (wend - wstart + 63) >> 6;
  const size_t rowb = (size_t)b * 2048;

  const int lane = tid & 63, wid = tid >> 6;
  const int cl = lane & 15;
  const int kq = (lane >> 4) * 8;
  const int rowg = lane >> 4;

  short8 aQ[2];
#pragma unroll
  for (int ks = 0; ks < 2; ++ks)
    aQ[ks] = *(const short8*)(qkv + (rowb + q0 + wid * 16 + cl) * 3072 + h * 64 + ks * 32 + kq);

  float m_i[4], l_i[4];
  f32x4 O[4];
#pragma unroll
  for (int r = 0; r < 4; ++r) { m_i[r] = -1.0e30f; l_i[r] = 0.f; }
#pragma unroll
  for (int nt = 0; nt < 4; ++nt) O[nt] = (f32x4){0.f, 0.f, 0.f, 0.f};

  for (int t = 0; t < ntile; ++t) {
    const int jbase = wstart + t * 64;
    __syncthreads();
    for (int idx = tid; idx < 512; idx += 256) {
      const int r = idx >> 3, c = idx & 7;
      const int jg = jbase + r;
      uint4 kv = {0u, 0u, 0u, 0u}, vv = {0u, 0u, 0u, 0u};
      if (jg < wend) {
        const size_t base = (rowb + jg) * 3072 + h * 64 + c * 8;
        kv = *(const uint4*)(qkv + base + 1024);
        vv = *(const uint4*)(qkv + base + 2048);
      }
      *(uint4*)&Ks[r * 72 + c * 8] = kv;
      const unsigned short* vs = (const unsigned short*)&vv;
#pragma unroll
      for (int ii = 0; ii < 8; ++ii) Vt[(c * 8 + ii) * 72 + r] = vs[ii];
    }
    __syncthreads();

    f32x4 S[4];
#pragma unroll
    for (int nt = 0; nt < 4; ++nt) S[nt] = (f32x4){0.f, 0.f, 0.f, 0.f};
#pragma unroll
    for (int nt = 0; nt < 4; ++nt)
#pragma unroll
      for (int ks = 0; ks < 2; ++ks) {
        const short8 bK = *(const short8*)&Ks[(nt * 16 + cl) * 72 + ks * 32 + kq];
        S[nt] = __builtin_amdgcn_mfma_f32_16x16x32_bf16(aQ[ks], bK, S[nt], 0, 0, 0);
      }

    float sc[4][4];
#pragma unroll
    for (int nt = 0; nt < 4; ++nt) {
      const int jg = jbase + nt * 16 + cl;
#pragma unroll
      for (int r = 0; r < 4; ++r) {
        const int i = q0 + wid * 16 + rowg * 4 + r;
        const bool v = (jg < wend) && (jg >= i - 128) && (jg <= i + 128);
        sc[nt][r] = v ? S[nt][r] * 0.125f : -1.0e30f;
      }
    }

    float alpha[4], p[4][4];
#pragma unroll
    for (int r = 0; r < 4; ++r) {
      float tm = fmaxf(fmaxf(sc[0][r], sc[1][r]), fmaxf(sc[2][r], sc[3][r]));
      tm = fmaxf(tm, __shfl_xor(tm, 1, 64));
      tm = fmaxf(tm, __shfl_xor(tm, 2, 64));
      tm = fmaxf(tm, __shfl_xor(tm, 4, 64));
      tm = fmaxf(tm, __shfl_xor(tm, 8, 64));
      const float mn = fmaxf(m_i[r], tm);
      alpha[r] = __expf(m_i[r] - mn);
      m_i[r] = mn;
      float ps = 0.f;
#pragma unroll
      for (int nt = 0; nt < 4; ++nt) { p[nt][r] = __expf(sc[nt][r] - mn); ps += p[nt][r]; }
      ps += __shfl_xor(ps, 1, 64);
      ps += __shfl_xor(ps, 2, 64);
      ps += __shfl_xor(ps, 4, 64);
      ps += __shfl_xor(ps, 8, 64);
      l_i[r] = l_i[r] * alpha[r] + ps;
    }

#pragma unroll
    for (int nt = 0; nt < 4; ++nt)
#pragma unroll
      for (int r = 0; r < 4; ++r)
        Ps[(wid * 16 + rowg * 4 + r) * 72 + nt * 16 + cl] = f2b(p[nt][r]);
    __syncthreads();

#pragma unroll
    for (int nt = 0; nt < 4; ++nt)
#pragma unroll
      for (int r = 0; r < 4; ++r) O[nt][r] *= alpha[r];
    short8 aP[2];
#pragma unroll
    for (int ks = 0; ks < 2; ++ks)
      aP[ks] = *(const short8*)&Ps[(wid * 16 + cl) * 72 + ks * 32 + kq];
#pragma unroll
    for (int nt = 0; nt < 4; ++nt)
#pragma unroll
      for (int ks = 0; ks < 2; ++ks) {
        const short8 bV = *(const short8*)&Vt[(nt * 16 + cl) * 72 + ks * 32 + kq];
        O[nt] = __builtin_amdgcn_mfma_f32_16x16x32_bf16(aP[ks], bV, O[nt], 0, 0, 0);
      }
  }

#pragma unroll
  for (int nt = 0; nt < 4; ++nt) {
    const int d = nt * 16 + cl;
#pragma unroll
    for (int r = 0; r < 4; ++r) {
      const int i = q0 + wid * 16 + rowg * 4 + r;
      ctx[(rowb + i) * 1024 + h * 64 + d] = f2b(O[nt][r] / l_i[r]);
    }
  }
}

// ---------------------------------------------------------------------------
// Residual + LayerNorm (unchanged). In-place safe per-row.
// ---------------------------------------------------------------------------
template<int AF32, int BF32, int OF32>
__global__ __launch_bounds__(256) void ln_k(
    const void* __restrict__ a, const void* __restrict__ b,
    const float* __restrict__ g, const float* __restrict__ be,
    void* __restrict__ o)
{
  __shared__ float rbuf[8];
  const int tid = threadIdx.x;
  const size_t base = (size_t)blockIdx.x * 1024;
  const int lane = tid & 63, wid = tid >> 6;

  float xv[4], s = 0.f, sq = 0.f;
#pragma unroll
  for (int t = 0; t < 4; ++t) {
    const int c = tid + t * 256;
    const float av = AF32 ? ((const float*)a)[base + c]
                          : b2f(((const unsigned short*)a)[base + c]);
    const float bv = BF32 ? ((const float*)b)[base + c]
                          : b2f(((const unsigned short*)b)[base + c]);
    const float x = av + bv;
    xv[t] = x; s += x; sq += x * x;
  }
  for (int o2 = 1; o2 < 64; o2 <<= 1) { s += __shfl_xor(s, o2, 64); sq += __shfl_xor(sq, o2, 64); }
  if (lane == 0) { rbuf[wid] = s; rbuf[wid + 4] = sq; }
  __syncthreads();
  s  = rbuf[0] + rbuf[1] + rbuf[2] + rbuf[3];
  sq = rbuf[4] + rbuf[5] + rbuf[6] + rbuf[7];
  const float mean = s * (1.0f / 1024.f);
  const float var = sq * (1.0f / 1024.f) - mean * mean;
  const float rstd = rsqrtf(var + 1e-5f);
#pragma unroll
  for (int t = 0; t < 4; ++t) {
    const int c = tid + t * 256;
    const float y = (xv[t] - mean) * rstd * g[c] + be[c];
    if (OF32) ((float*)o)[base + c] = y;
    else      ((unsigned short*)o)[base + c] = f2b(y);
  }
}

// ---------------------------------------------------------------------------
extern "C" void kernel_launch(void* const* d_in, const int* in_sizes, int n_in,
                              void* d_out, int out_size, void* d_ws, size_t ws_size,
                              hipStream_t stream)
{
  (void)in_sizes; (void)n_in; (void)out_size; (void)ws_size;
  const float* src   = (const float*)d_in[0];
  const float* w_in  = (const float*)d_in[1];
  const float* b_in  = (const float*)d_in[2];
  const float* w_out = (const float*)d_in[3];
  const float* b_out = (const float*)d_in[4];
  const float* w1    = (const float*)d_in[5];
  const float* b1    = (const float*)d_in[6];
  const float* w2    = (const float*)d_in[7];
  const float* b2    = (const float*)d_in[8];
  const float* g1    = (const float*)d_in[9];
  const float* be1   = (const float*)d_in[10];
  const float* g2    = (const float*)d_in[11];
  const float* be2   = (const float*)d_in[12];

  char* ws = (char*)d_ws;
  unsigned short* srcb  = (unsigned short*)(ws);                 // [0, 8388608)
  unsigned short* x1b   = srcb;                                  // in-place over srcb
  unsigned short* qkv   = (unsigned short*)(ws + 8388608);       // [8388608, 33554432)
  unsigned short* ctx   = (unsigned short*)(ws + 33554432);      // [33554432, 41943040)
  unsigned short* attnb = (unsigned short*)(ws + 8388608);       // reuse qkv head
  unsigned short* ff1   = (unsigned short*)(ws + 8388608);       // [8388608, 41943040)
  unsigned short* wslot = (unsigned short*)(ws + 41943040);      // [41943040, 50331648)
  float*          outf  = (float*)d_out;

  // 0) convert src -> bf16 srcb
  conv_k<<<dim3(2048), 256, 0, stream>>>(src, srcb, 4194304);
  // 1) convert in_proj_w; QKV projection -> bf16 qkv
  conv_k<<<dim3(1536), 256, 0, stream>>>(w_in, wslot, 3145728);
  gemm128<0, 0><<<dim3(24, 32), 256, 0, stream>>>(srcb, wslot, b_in, qkv, 4096, 3072, 1024);
  // 2) banded MFMA flash attention -> bf16 ctx
  attn_mfma<<<dim3(1024), 256, 0, stream>>>(qkv, ctx);
  // 3) convert out_w; output projection (gemm64) -> bf16 attnb
  conv_k<<<dim3(512), 256, 0, stream>>>(w_out, wslot, 1048576);
  gemm64<0, 0><<<dim3(8, 64, 1), 256, 0, stream>>>(ctx, wslot, b_out, attnb, 4096, 1024, 1024);
  // 4) LN1(srcb bf16 + attnb bf16) -> bf16 x1b (in-place over srcb)
  ln_k<0, 0, 0><<<dim3(4096), 256, 0, stream>>>(srcb, attnb, g1, be1, x1b);
  // 5) convert lin1_w; FF1 + ReLU -> bf16 ff1
  conv_k<<<dim3(2048), 256, 0, stream>>>(w1, wslot, 4194304);
  gemm128<1, 0><<<dim3(32, 32), 256, 0, stream>>>(x1b, wslot, b1, ff1, 4096, 4096, 1024);
  // 6) convert lin2_w; FF2 split-K=2 (1024 blocks = 4/CU), atomicAdd into
  //    pre-zeroed d_out
  conv_k<<<dim3(2048), 256, 0, stream>>>(w2, wslot, 4194304);
  hipMemsetAsync(outf, 0, 16777216, stream);
  gemm64<1, 1><<<dim3(8, 64, 2), 256, 0, stream>>>(ff1, wslot, b2, outf, 4096, 1024, 4096);
  // 7) LN2(x1b bf16 + d_out f32) -> f32 d_out (in-place, per-row safe)
  ln_k<0, 1, 1><<<dim3(4096), 256, 0, stream>>>(x1b, outf, g2, be2, outf);
}